// Round 13
// baseline (277.864 us; speedup 1.0000x reference)
//
#include <hip/hip_runtime.h>
#include <hip/hip_bf16.h>
#include <cstdint>

#define NNODES 100000
#define NEDGES 1600000
#define NGRAPHS 64
#define DIM 128

#define NB 391          // buckets: dst >> 8 (256 nodes each)
#define BSHIFT 8
#define SC_BLOCKS 200
#define SC_EPB (NEDGES / SC_BLOCKS)        // 8000
#define EB_CAP 5000                        // max edges per bucket (mean 4096)

typedef __attribute__((ext_vector_type(8))) short bf16x8;
typedef __attribute__((ext_vector_type(4))) float f32x4;

__device__ inline ushort f2bf(float f) {
  __hip_bfloat16 h = __float2bfloat16(f);
  return __builtin_bit_cast(ushort, h);
}
__device__ inline float bf2f(ushort u) {
  return __uint_as_float(((unsigned)u) << 16);
}
__device__ inline unsigned fkey(float f) {
  unsigned b = __float_as_uint(f);
  return (b & 0x80000000u) ? ~b : (b | 0x80000000u);
}
__device__ inline float fdecode(unsigned k) {
  unsigned b = (k & 0x80000000u) ? (k & 0x7FFFFFFFu) : ~k;
  return __uint_as_float(b);
}

// ---------------- merged: per-block bucket hist (blocks 0..199) + prep (blocks 200..238) ----------------

__global__ __launch_bounds__(256) void histprep_kernel(const int* __restrict__ dst,
                                                       int* __restrict__ blockhist,
                                                       int* __restrict__ bhist,
                                                       const float* __restrict__ et,
                                                       const float* __restrict__ ei,
                                                       const float* __restrict__ W0,
                                                       const float* __restrict__ W1,
                                                       const float* __restrict__ W2,
                                                       float* __restrict__ TW,
                                                       ushort* __restrict__ wbf) {
  int tid = threadIdx.x;
  if (blockIdx.x < SC_BLOCKS) {
    __shared__ int bh[NB];
    for (int k = tid; k < NB; k += 256) bh[k] = 0;
    __syncthreads();
    int base = blockIdx.x * SC_EPB;
    for (int o = tid * 4; o < SC_EPB; o += 1024) {
      int4 d4 = *(const int4*)(dst + base + o);
      atomicAdd(&bh[d4.x >> BSHIFT], 1);
      atomicAdd(&bh[d4.y >> BSHIFT], 1);
      atomicAdd(&bh[d4.z >> BSHIFT], 1);
      atomicAdd(&bh[d4.w >> BSHIFT], 1);
    }
    __syncthreads();
    for (int k = tid; k < NB; k += 256) {
      blockhist[blockIdx.x * NB + k] = bh[k];
      if (bh[k]) atomicAdd(&bhist[k], bh[k]);
    }
  } else if (tid < 128) {
    int b = blockIdx.x - SC_BLOCKS;
    if (b < 7) {
      const float* in = (b < 4) ? (et + b * DIM) : (ei + (b - 4) * DIM);
      float acc = 0.f;
      for (int k = 0; k < DIM; ++k) acc += in[k] * W0[k * DIM + tid];
      TW[b * DIM + tid] = acc;
    } else {
      int m = (b - 7) >> 4;               // 0: W1, 1: W2
      int blk = (b - 7) & 15;
      const float* w = m ? W2 : W1;
      ushort* o = wbf + (size_t)m * DIM * DIM;
      int base = blk * 1024 + tid * 8;
      float4 a = *(const float4*)(w + base);
      float4 c = *(const float4*)(w + base + 4);
      uint4 r;
      r.x = ((unsigned)f2bf(a.y) << 16) | f2bf(a.x);
      r.y = ((unsigned)f2bf(a.w) << 16) | f2bf(a.z);
      r.z = ((unsigned)f2bf(c.y) << 16) | f2bf(c.x);
      r.w = ((unsigned)f2bf(c.w) << 16) | f2bf(c.z);
      *(uint4*)(o + base) = r;
    }
  }
}

// NB blocks x 512 thr: global bucket base (redundant scan) + per-block column scan.
__global__ __launch_bounds__(512) void scanB_kernel(const int* __restrict__ bhist,
                                                    const int* __restrict__ blockhist,
                                                    int* __restrict__ bbase,
                                                    int* __restrict__ blockbase,
                                                    int* __restrict__ offs) {
  __shared__ int gb[512];
  __shared__ int col[512];
  int tid = threadIdx.x;
  int b = blockIdx.x;
  int v = (tid < NB) ? bhist[tid] : 0;
  gb[tid] = v;
  __syncthreads();
  for (int o = 1; o < 512; o <<= 1) {
    int t = (tid >= o) ? gb[tid - o] : 0;
    __syncthreads();
    gb[tid] += t;
    __syncthreads();
  }
  int excl_b = gb[b] - bhist[b];
  int c = (tid < SC_BLOCKS) ? blockhist[tid * NB + b] : 0;
  col[tid] = c;
  __syncthreads();
  for (int o = 1; o < 512; o <<= 1) {
    int t = (tid >= o) ? col[tid - o] : 0;
    __syncthreads();
    col[tid] += t;
    __syncthreads();
  }
  if (tid < SC_BLOCKS) blockbase[tid * NB + b] = excl_b + col[tid] - c;
  if (tid == 0) {
    bbase[b] = excl_b;
    if (b == 0) { bbase[NB] = NEDGES; offs[NNODES] = NEDGES; }
  }
}

__global__ __launch_bounds__(256) void scatter2_kernel(const int* __restrict__ src,
                                                       const int* __restrict__ dst,
                                                       const int* __restrict__ blockbase,
                                                       unsigned* __restrict__ gbuf) {
  __shared__ int lcur[NB];
  int tid = threadIdx.x;
  for (int k = tid; k < NB; k += 256) lcur[k] = blockbase[blockIdx.x * NB + k];
  __syncthreads();
  int base = blockIdx.x * SC_EPB;
  for (int o = tid * 4; o < SC_EPB; o += 1024) {
    int4 s4 = *(const int4*)(src + base + o);
    int4 d4 = *(const int4*)(dst + base + o);
    int ss[4] = {s4.x, s4.y, s4.z, s4.w};
    int dd[4] = {d4.x, d4.y, d4.z, d4.w};
#pragma unroll
    for (int u = 0; u < 4; ++u) {
      int bk = dd[u] >> BSHIFT;
      unsigned rec = (unsigned)ss[u] | ((unsigned)(dd[u] & 255) << 17);
      int pos = atomicAdd(&lcur[bk], 1);
      gbuf[pos] = rec;
    }
  }
}

// one block per bucket (256 nodes): counting sort by local dst; emits csr_src, offs, dinv, pk
__global__ __launch_bounds__(256) void bucket_sort(const unsigned* __restrict__ gbuf,
                                                   const int* __restrict__ bhist,
                                                   const int* __restrict__ bbase,
                                                   const int* __restrict__ nt,
                                                   const int* __restrict__ nv,
                                                   int* __restrict__ csr_src,
                                                   int* __restrict__ offs,
                                                   float* __restrict__ dinv,
                                                   unsigned* __restrict__ pk) {
  __shared__ int lhist[256];
  __shared__ int lscan[256];
  __shared__ int lcur2[256];
  __shared__ int lcsr[EB_CAP];
  int tid = threadIdx.x;
  int b = blockIdx.x;
  int ebase = bbase[b];
  int bsize = bhist[b];
  lhist[tid] = 0;
  lcur2[tid] = 0;
  __syncthreads();
  for (int k = tid; k < bsize; k += 256)
    atomicAdd(&lhist[(gbuf[ebase + k] >> 17) & 255], 1);
  __syncthreads();
  lscan[tid] = lhist[tid];
  __syncthreads();
  for (int o = 1; o < 256; o <<= 1) {
    int a = (tid >= o) ? lscan[tid - o] : 0;
    __syncthreads();
    lscan[tid] += a;
    __syncthreads();
  }
  int i = (b << BSHIFT) + tid;
  if (i < NNODES) {
    int c = lhist[tid];
    offs[i] = ebase + (lscan[tid] - c);
    float dv = rsqrtf((float)c + 1.0f);
    dinv[i] = dv;
    pk[i] = (__float_as_uint(dv) & 0xFFFFFFF0u) |
            ((unsigned)nt[i] << 2) | (unsigned)nv[i];
  }
  for (int k = tid; k < bsize; k += 256) {
    unsigned e = gbuf[ebase + k];
    int l = (e >> 17) & 255;
    int p = atomicAdd(&lcur2[l], 1);
    int pos = (lscan[l] - lhist[l]) + p;
    if (pos < EB_CAP) lcsr[pos] = (int)(e & 0x1FFFFu);
  }
  __syncthreads();
  for (int k = tid; k < bsize; k += 256) csr_src[ebase + k] = lcsr[k];
}

// ---------------- layer 0: dictionary coefficients (pk: 1 gather/edge) ----------------

__device__ inline void pk_accum(unsigned p, float& c0, float& c1, float& c2, float& c3,
                                float& c4, float& c5, float& c6) {
  float dv = __uint_as_float(p & 0xFFFFFFF0u);
  int t = (p >> 2) & 3, v = p & 3;
  c0 += (t == 0) ? dv : 0.f;
  c1 += (t == 1) ? dv : 0.f;
  c2 += (t == 2) ? dv : 0.f;
  c3 += (t == 3) ? dv : 0.f;
  c4 += (v == 0) ? dv : 0.f;
  c5 += (v == 1) ? dv : 0.f;
  c6 += (v == 2) ? dv : 0.f;
}

__global__ __launch_bounds__(256) void coef_kernel(const int* __restrict__ offs,
                                                   const int* __restrict__ csr_src,
                                                   const unsigned* __restrict__ pk,
                                                   float* __restrict__ Cbuf) {
  int gid = blockIdx.x * 256 + threadIdx.x;
  int i = gid >> 2;
  int sl = gid & 3;
  if (i >= NNODES) return;
  int s0 = offs[i], s1 = offs[i + 1];
  float c0 = 0.f, c1 = 0.f, c2 = 0.f, c3 = 0.f, c4 = 0.f, c5 = 0.f, c6 = 0.f;
  int j = s0 + sl;
  for (; j + 28 < s1; j += 32) {
    int s_[8];
#pragma unroll
    for (int u = 0; u < 8; ++u) s_[u] = csr_src[j + 4 * u];
    unsigned p_[8];
#pragma unroll
    for (int u = 0; u < 8; ++u) p_[u] = pk[s_[u]];
#pragma unroll
    for (int u = 0; u < 8; ++u) pk_accum(p_[u], c0, c1, c2, c3, c4, c5, c6);
  }
  for (; j < s1; j += 4) pk_accum(pk[csr_src[j]], c0, c1, c2, c3, c4, c5, c6);
#pragma unroll
  for (int o = 1; o < 4; o <<= 1) {
    c0 += __shfl_xor(c0, o);
    c1 += __shfl_xor(c1, o);
    c2 += __shfl_xor(c2, o);
    c3 += __shfl_xor(c3, o);
    c4 += __shfl_xor(c4, o);
    c5 += __shfl_xor(c5, o);
    c6 += __shfl_xor(c6, o);
  }
  if (sl == 0) {
    unsigned pb = pk[i];
    float di = __uint_as_float(pb & 0xFFFFFFF0u);
    int t = (pb >> 2) & 3, v = pb & 3;
    c0 += (t == 0) ? di : 0.f;
    c1 += (t == 1) ? di : 0.f;
    c2 += (t == 2) ? di : 0.f;
    c3 += (t == 3) ? di : 0.f;
    c4 += (v == 0) ? di : 0.f;
    c5 += (v == 1) ? di : 0.f;
    c6 += (v == 2) ? di : 0.f;
    float4 lo = {c0, c1, c2, c3};
    float4 hi = {c4, c5, c6, 0.f};
    *(float4*)(Cbuf + (size_t)i * 8) = lo;
    *(float4*)(Cbuf + (size_t)i * 8 + 4) = hi;
  }
}

// ---------------- fused layer-1 GEMM: xws = dinv * (relu(dinv*(C@TW)+b0) @ W1) ----------------

__global__ __launch_bounds__(256) void gemm1_kernel(const float* __restrict__ Cbuf,
                                                    const float* __restrict__ TW,
                                                    const float* __restrict__ b0,
                                                    const ushort* __restrict__ wb,
                                                    const float* __restrict__ dinv,
                                                    ushort* __restrict__ out) {
  __shared__ ushort Ws[32 * 64 * 8];  // 32 KiB, B-fragment order
  __shared__ float TWs[7 * 128];
  __shared__ float b0s[128];
  int tid = threadIdx.x;
  for (int g = tid; g < 2048; g += 256) {
    int kt = g >> 6, l = g & 63;
    int ks = kt >> 3, t = kt & 7;
    int kb = ks * 32 + ((l >> 4) << 3);
    int col = t * 16 + (l & 15);
#pragma unroll
    for (int j = 0; j < 8; ++j) Ws[g * 8 + j] = wb[(kb + j) * DIM + col];
  }
  for (int g = tid; g < 896; g += 256) TWs[g] = TW[g];
  if (tid < 128) b0s[tid] = b0[tid];
  __syncthreads();
  int w = tid >> 6, lane = tid & 63;
  for (int tile = blockIdx.x * 4 + w; tile < NNODES / 16; tile += gridDim.x * 4) {
    int row0 = tile * 16;
    int arow = row0 + (lane & 15);
    float di = dinv[arow];
    float4 Clo = *(const float4*)(Cbuf + (size_t)arow * 8);
    float4 Chi = *(const float4*)(Cbuf + (size_t)arow * 8 + 4);
    float C[7] = {Clo.x, Clo.y, Clo.z, Clo.w, Chi.x, Chi.y, Chi.z};
    f32x4 acc[8];
#pragma unroll
    for (int t = 0; t < 8; ++t) acc[t] = {0.f, 0.f, 0.f, 0.f};
#pragma unroll
    for (int ks = 0; ks < 4; ++ks) {
      int d0 = ((lane >> 4) << 3) + ks * 32;
      bf16x8 a;
#pragma unroll
      for (int d = 0; d < 8; ++d) {
        float dot = 0.f;
#pragma unroll
        for (int k = 0; k < 7; ++k) dot += C[k] * TWs[k * 128 + d0 + d];
        float s = fmaxf(di * dot + b0s[d0 + d], 0.f);
        a[d] = (short)f2bf(s);
      }
#pragma unroll
      for (int t = 0; t < 8; ++t) {
        bf16x8 bfr = *(const bf16x8*)&Ws[((ks * 8 + t) * 64 + lane) * 8];
        acc[t] = __builtin_amdgcn_mfma_f32_16x16x32_bf16(a, bfr, acc[t], 0, 0, 0);
      }
    }
    int rbase = row0 + ((lane >> 4) << 2);
    int cbase = lane & 15;
    float4 dv = *(const float4*)(dinv + rbase);
    float dvr[4] = {dv.x, dv.y, dv.z, dv.w};
#pragma unroll
    for (int t = 0; t < 8; ++t)
#pragma unroll
      for (int r = 0; r < 4; ++r)
        out[(size_t)(rbase + r) * DIM + t * 16 + cbase] = f2bf(acc[t][r] * dvr[r]);
  }
}

// ---------------- MFMA GEMM (layer 2): xws = dinv * (h @ W) ----------------

__global__ __launch_bounds__(256) void gemm_kernel(const ushort* __restrict__ h,
                                                   const ushort* __restrict__ wb,
                                                   const float* __restrict__ dinv,
                                                   ushort* __restrict__ out) {
  __shared__ ushort Ws[32 * 64 * 8];
  int tid = threadIdx.x;
  for (int g = tid; g < 2048; g += 256) {
    int kt = g >> 6, l = g & 63;
    int ks = kt >> 3, t = kt & 7;
    int kb = ks * 32 + ((l >> 4) << 3);
    int col = t * 16 + (l & 15);
#pragma unroll
    for (int j = 0; j < 8; ++j) Ws[g * 8 + j] = wb[(kb + j) * DIM + col];
  }
  __syncthreads();
  int w = tid >> 6, lane = tid & 63;
  for (int tile = blockIdx.x * 4 + w; tile < NNODES / 16; tile += gridDim.x * 4) {
    int row0 = tile * 16;
    const ushort* hrow = h + (size_t)(row0 + (lane & 15)) * DIM + ((lane >> 4) << 3);
    f32x4 acc[8];
#pragma unroll
    for (int t = 0; t < 8; ++t) acc[t] = {0.f, 0.f, 0.f, 0.f};
#pragma unroll
    for (int ks = 0; ks < 4; ++ks) {
      bf16x8 a = *(const bf16x8*)(hrow + ks * 32);
#pragma unroll
      for (int t = 0; t < 8; ++t) {
        bf16x8 b = *(const bf16x8*)&Ws[((ks * 8 + t) * 64 + lane) * 8];
        acc[t] = __builtin_amdgcn_mfma_f32_16x16x32_bf16(a, b, acc[t], 0, 0, 0);
      }
    }
    int rbase = row0 + ((lane >> 4) << 2);
    int cbase = lane & 15;
    float4 dv = *(const float4*)(dinv + rbase);
    float dvr[4] = {dv.x, dv.y, dv.z, dv.w};
#pragma unroll
    for (int t = 0; t < 8; ++t)
#pragma unroll
      for (int r = 0; r < 4; ++r)
        out[(size_t)(rbase + r) * DIM + t * 16 + cbase] = f2bf(acc[t][r] * dvr[r]);
  }
}

// ---------------- aggregation: one wave per node, 8B/lane, 2 rows per instruction ----------------
// half = lane>>5 processes edges of parity `half`; lane covers dims [4*(lane&31), +4)

__global__ __launch_bounds__(256, 8) void agg_kernel(const ushort* __restrict__ xws,
                                                     const int* __restrict__ offs,
                                                     const int* __restrict__ csr_src,
                                                     const float* __restrict__ dinv,
                                                     const float* __restrict__ bias,
                                                     ushort* __restrict__ outb, int relu) {
  int i = blockIdx.x * 4 + (threadIdx.x >> 6);
  if (i >= NNODES) return;
  int lane = threadIdx.x & 63;
  int half = lane >> 5;
  int sub = lane & 31;
  int s0 = offs[i], s1 = offs[i + 1];
  float a0 = 0.f, a1 = 0.f, a2 = 0.f, a3 = 0.f;
  int j = s0 + half;
  // 8 rows per half per batch (16 edges per wave-batch)
  for (; j + 14 < s1; j += 16) {
    int s_[8];
#pragma unroll
    for (int u = 0; u < 8; ++u) s_[u] = csr_src[j + 2 * u];
    uint2 p_[8];
#pragma unroll
    for (int u = 0; u < 8; ++u)
      p_[u] = *(const uint2*)(xws + (size_t)s_[u] * DIM + sub * 4);
#pragma unroll
    for (int u = 0; u < 8; ++u) {
      a0 += bf2f((ushort)(p_[u].x & 0xffffu));
      a1 += bf2f((ushort)(p_[u].x >> 16));
      a2 += bf2f((ushort)(p_[u].y & 0xffffu));
      a3 += bf2f((ushort)(p_[u].y >> 16));
    }
  }
  for (; j + 6 < s1; j += 8) {
    int s_[4];
#pragma unroll
    for (int u = 0; u < 4; ++u) s_[u] = csr_src[j + 2 * u];
    uint2 p_[4];
#pragma unroll
    for (int u = 0; u < 4; ++u)
      p_[u] = *(const uint2*)(xws + (size_t)s_[u] * DIM + sub * 4);
#pragma unroll
    for (int u = 0; u < 4; ++u) {
      a0 += bf2f((ushort)(p_[u].x & 0xffffu));
      a1 += bf2f((ushort)(p_[u].x >> 16));
      a2 += bf2f((ushort)(p_[u].y & 0xffffu));
      a3 += bf2f((ushort)(p_[u].y >> 16));
    }
  }
  for (; j < s1; j += 2) {
    int s = csr_src[j];
    uint2 p = *(const uint2*)(xws + (size_t)s * DIM + sub * 4);
    a0 += bf2f((ushort)(p.x & 0xffffu));
    a1 += bf2f((ushort)(p.x >> 16));
    a2 += bf2f((ushort)(p.y & 0xffffu));
    a3 += bf2f((ushort)(p.y >> 16));
  }
  if (half == 0) {  // self contribution once
    uint2 p = *(const uint2*)(xws + (size_t)i * DIM + sub * 4);
    a0 += bf2f((ushort)(p.x & 0xffffu));
    a1 += bf2f((ushort)(p.x >> 16));
    a2 += bf2f((ushort)(p.y & 0xffffu));
    a3 += bf2f((ushort)(p.y >> 16));
  }
  a0 += __shfl_xor(a0, 32);
  a1 += __shfl_xor(a1, 32);
  a2 += __shfl_xor(a2, 32);
  a3 += __shfl_xor(a3, 32);
  if (half == 0) {
    float di = dinv[i];
    float4 bb = *(const float4*)(bias + sub * 4);
    float v0 = di * a0 + bb.x;
    float v1 = di * a1 + bb.y;
    float v2 = di * a2 + bb.z;
    float v3 = di * a3 + bb.w;
    if (relu) {
      v0 = fmaxf(v0, 0.f); v1 = fmaxf(v1, 0.f);
      v2 = fmaxf(v2, 0.f); v3 = fmaxf(v3, 0.f);
    }
    uint2 o;
    o.x = ((unsigned)f2bf(v1) << 16) | f2bf(v0);
    o.y = ((unsigned)f2bf(v3) << 16) | f2bf(v2);
    *(uint2*)(outb + (size_t)i * DIM + sub * 4) = o;
  }
}

// ---------------- readout (bf16 h) ----------------

__global__ __launch_bounds__(128) void readout_kernel(const ushort* __restrict__ h,
                                                      const int* __restrict__ batch,
                                                      unsigned* __restrict__ gmaxk,
                                                      float* __restrict__ gsum) {
  int d = threadIdx.x;
  int start = blockIdx.x * 128;
  if (start >= NNODES) return;
  int end = min(start + 128, NNODES);
  int cur = batch[start];
  float s = 0.f, m = -INFINITY;
  for (int i = start; i < end; ++i) {
    int g = batch[i];
    float v = bf2f(h[(size_t)i * DIM + d]);
    if (g != cur) {
      atomicAdd(&gsum[cur * DIM + d], s);
      atomicMax(&gmaxk[cur * DIM + d], fkey(m));
      cur = g; s = 0.f; m = -INFINITY;
    }
    s += v;
    m = fmaxf(m, v);
  }
  atomicAdd(&gsum[cur * DIM + d], s);
  atomicMax(&gmaxk[cur * DIM + d], fkey(m));
}

__global__ void pack_kernel(const unsigned* __restrict__ gmaxk,
                            const float* __restrict__ gsum, float* __restrict__ out) {
  int idx = blockIdx.x * blockDim.x + threadIdx.x;
  if (idx >= NGRAPHS * 256) return;
  int g = idx >> 8, d = idx & 255;
  float v = (d < 128) ? fdecode(gmaxk[g * DIM + d]) : gsum[g * DIM + (d - 128)];
  out[idx] = rintf(v * 1000.0f) / 1000.0f;
}

// ---------------- launch ----------------

extern "C" void kernel_launch(void* const* d_in, const int* in_sizes, int n_in,
                              void* d_out, int out_size, void* d_ws, size_t ws_size,
                              hipStream_t stream) {
  const int* node_type = (const int*)d_in[0];
  const int* ninv      = (const int*)d_in[1];
  const int* edge      = (const int*)d_in[2];
  const int* batch     = (const int*)d_in[3];
  const float* emb_type = (const float*)d_in[4];
  const float* emb_inv  = (const float*)d_in[5];
  const float* W0 = (const float*)d_in[6];
  const float* B[3] = {(const float*)d_in[7], (const float*)d_in[9], (const float*)d_in[11]};
  const float* W1 = (const float*)d_in[8];
  const float* W2 = (const float*)d_in[10];
  const int* srcp = edge;
  const int* dstp = edge + NEDGES;
  float* out = (float*)d_out;

  char* ws = (char*)d_ws;
  auto alloc = [&](size_t bytes) {
    char* p = ws;
    ws += (bytes + 255) & ~(size_t)255;
    return p;
  };
  ushort* hA     = (ushort*)alloc((size_t)NNODES * DIM * 2);
  ushort* xws    = (ushort*)alloc((size_t)NNODES * DIM * 2);
  float* dinv    = (float*)alloc((size_t)NNODES * 4);
  unsigned* pk   = (unsigned*)alloc((size_t)NNODES * 4);
  int* offs      = (int*)alloc((size_t)(NNODES + 1) * 4);
  int* csr_src   = (int*)alloc((size_t)NEDGES * 4);
  unsigned* gbuf = (unsigned*)alloc((size_t)NEDGES * 4);
  float* Cbuf    = (float*)alloc((size_t)NNODES * 8 * 4);
  unsigned* gmaxk = (unsigned*)alloc((size_t)NGRAPHS * DIM * 4);   // contiguous with
  float* gsum    = (float*)alloc((size_t)NGRAPHS * DIM * 4);       // gsum and bhist
  int* bhist     = (int*)alloc((size_t)NB * 4);
  int* bbase     = (int*)alloc((size_t)(NB + 1) * 4);
  int* blockhist = (int*)alloc((size_t)SC_BLOCKS * NB * 4);
  int* blockbase = (int*)alloc((size_t)SC_BLOCKS * NB * 4);
  float* TW      = (float*)alloc((size_t)7 * DIM * 4);
  ushort* wbf    = (ushort*)alloc((size_t)2 * DIM * DIM * 2);

  // gmaxk | gsum | bhist are contiguous
  hipMemsetAsync(gmaxk, 0, (size_t)NGRAPHS * DIM * 4 * 2 + NB * 4, stream);

  histprep_kernel<<<SC_BLOCKS + 39, 256, 0, stream>>>(dstp, blockhist, bhist,
                                                      emb_type, emb_inv, W0, W1, W2,
                                                      TW, wbf);
  scanB_kernel<<<NB, 512, 0, stream>>>(bhist, blockhist, bbase, blockbase, offs);
  scatter2_kernel<<<SC_BLOCKS, 256, 0, stream>>>(srcp, dstp, blockbase, gbuf);
  bucket_sort<<<NB, 256, 0, stream>>>(gbuf, bhist, bbase, node_type, ninv,
                                      csr_src, offs, dinv, pk);

  coef_kernel<<<(NNODES * 4 + 255) / 256, 256, 0, stream>>>(offs, csr_src, pk, Cbuf);

  // layer 1: fused h1-synthesis GEMM, then aggregate
  gemm1_kernel<<<1024, 256, 0, stream>>>(Cbuf, TW, B[0], wbf, dinv, xws);
  agg_kernel<<<NNODES / 4, 256, 0, stream>>>(xws, offs, csr_src, dinv, B[1], hA, 1);

  // layer 2
  gemm_kernel<<<1024, 256, 0, stream>>>(hA, wbf + (size_t)DIM * DIM, dinv, xws);
  agg_kernel<<<NNODES / 4, 256, 0, stream>>>(xws, offs, csr_src, dinv, B[2], hA, 0);

  readout_kernel<<<(NNODES + 127) / 128, 128, 0, stream>>>(hA, batch, gmaxk, gsum);
  pack_kernel<<<64, 256, 0, stream>>>(gmaxk, gsum, out);
}

// Round 14
// 273.351 us; speedup vs baseline: 1.0165x; 1.0165x over previous
//
#include <hip/hip_runtime.h>
#include <hip/hip_bf16.h>
#include <cstdint>

#define NNODES 100000
#define NEDGES 1600000
#define NGRAPHS 64
#define DIM 128

#define NB 391          // buckets: dst >> 8 (256 nodes each)
#define BSHIFT 8
#define SC_BLOCKS 200
#define SC_EPB (NEDGES / SC_BLOCKS)        // 8000
#define EB_CAP 5000                        // max edges per bucket (mean 4096)

typedef __attribute__((ext_vector_type(8))) short bf16x8;
typedef __attribute__((ext_vector_type(4))) float f32x4;

__device__ inline ushort f2bf(float f) {
  __hip_bfloat16 h = __float2bfloat16(f);
  return __builtin_bit_cast(ushort, h);
}
__device__ inline float bf2f(ushort u) {
  return __uint_as_float(((unsigned)u) << 16);
}
__device__ inline unsigned fkey(float f) {
  unsigned b = __float_as_uint(f);
  return (b & 0x80000000u) ? ~b : (b | 0x80000000u);
}
__device__ inline float fdecode(unsigned k) {
  unsigned b = (k & 0x80000000u) ? (k & 0x7FFFFFFFu) : ~k;
  return __uint_as_float(b);
}

// ---------------- merged: per-block bucket hist (blocks 0..199) + prep (blocks 200..238) ----------------

__global__ __launch_bounds__(256) void histprep_kernel(const int* __restrict__ dst,
                                                       int* __restrict__ blockhist,
                                                       int* __restrict__ bhist,
                                                       const float* __restrict__ et,
                                                       const float* __restrict__ ei,
                                                       const float* __restrict__ W0,
                                                       const float* __restrict__ W1,
                                                       const float* __restrict__ W2,
                                                       float* __restrict__ TW,
                                                       ushort* __restrict__ wbf) {
  int tid = threadIdx.x;
  if (blockIdx.x < SC_BLOCKS) {
    __shared__ int bh[NB];
    for (int k = tid; k < NB; k += 256) bh[k] = 0;
    __syncthreads();
    int base = blockIdx.x * SC_EPB;
    for (int o = tid * 4; o < SC_EPB; o += 1024) {
      int4 d4 = *(const int4*)(dst + base + o);
      atomicAdd(&bh[d4.x >> BSHIFT], 1);
      atomicAdd(&bh[d4.y >> BSHIFT], 1);
      atomicAdd(&bh[d4.z >> BSHIFT], 1);
      atomicAdd(&bh[d4.w >> BSHIFT], 1);
    }
    __syncthreads();
    for (int k = tid; k < NB; k += 256) {
      blockhist[blockIdx.x * NB + k] = bh[k];
      if (bh[k]) atomicAdd(&bhist[k], bh[k]);
    }
  } else if (tid < 128) {
    int b = blockIdx.x - SC_BLOCKS;
    if (b < 7) {
      const float* in = (b < 4) ? (et + b * DIM) : (ei + (b - 4) * DIM);
      float acc = 0.f;
      for (int k = 0; k < DIM; ++k) acc += in[k] * W0[k * DIM + tid];
      TW[b * DIM + tid] = acc;
    } else {
      int m = (b - 7) >> 4;               // 0: W1, 1: W2
      int blk = (b - 7) & 15;
      const float* w = m ? W2 : W1;
      ushort* o = wbf + (size_t)m * DIM * DIM;
      int base = blk * 1024 + tid * 8;
      float4 a = *(const float4*)(w + base);
      float4 c = *(const float4*)(w + base + 4);
      uint4 r;
      r.x = ((unsigned)f2bf(a.y) << 16) | f2bf(a.x);
      r.y = ((unsigned)f2bf(a.w) << 16) | f2bf(a.z);
      r.z = ((unsigned)f2bf(c.y) << 16) | f2bf(c.x);
      r.w = ((unsigned)f2bf(c.w) << 16) | f2bf(c.z);
      *(uint4*)(o + base) = r;
    }
  }
}

// NB blocks x 512 thr: global bucket base (redundant scan) + per-block column scan.
__global__ __launch_bounds__(512) void scanB_kernel(const int* __restrict__ bhist,
                                                    const int* __restrict__ blockhist,
                                                    int* __restrict__ bbase,
                                                    int* __restrict__ blockbase,
                                                    int* __restrict__ offs) {
  __shared__ int gb[512];
  __shared__ int col[512];
  int tid = threadIdx.x;
  int b = blockIdx.x;
  int v = (tid < NB) ? bhist[tid] : 0;
  gb[tid] = v;
  __syncthreads();
  for (int o = 1; o < 512; o <<= 1) {
    int t = (tid >= o) ? gb[tid - o] : 0;
    __syncthreads();
    gb[tid] += t;
    __syncthreads();
  }
  int excl_b = gb[b] - bhist[b];
  int c = (tid < SC_BLOCKS) ? blockhist[tid * NB + b] : 0;
  col[tid] = c;
  __syncthreads();
  for (int o = 1; o < 512; o <<= 1) {
    int t = (tid >= o) ? col[tid - o] : 0;
    __syncthreads();
    col[tid] += t;
    __syncthreads();
  }
  if (tid < SC_BLOCKS) blockbase[tid * NB + b] = excl_b + col[tid] - c;
  if (tid == 0) {
    bbase[b] = excl_b;
    if (b == 0) { bbase[NB] = NEDGES; offs[NNODES] = NEDGES; }
  }
}

__global__ __launch_bounds__(256) void scatter2_kernel(const int* __restrict__ src,
                                                       const int* __restrict__ dst,
                                                       const int* __restrict__ blockbase,
                                                       unsigned* __restrict__ gbuf) {
  __shared__ int lcur[NB];
  int tid = threadIdx.x;
  for (int k = tid; k < NB; k += 256) lcur[k] = blockbase[blockIdx.x * NB + k];
  __syncthreads();
  int base = blockIdx.x * SC_EPB;
  for (int o = tid * 4; o < SC_EPB; o += 1024) {
    int4 s4 = *(const int4*)(src + base + o);
    int4 d4 = *(const int4*)(dst + base + o);
    int ss[4] = {s4.x, s4.y, s4.z, s4.w};
    int dd[4] = {d4.x, d4.y, d4.z, d4.w};
#pragma unroll
    for (int u = 0; u < 4; ++u) {
      int bk = dd[u] >> BSHIFT;
      unsigned rec = (unsigned)ss[u] | ((unsigned)(dd[u] & 255) << 17);
      int pos = atomicAdd(&lcur[bk], 1);
      gbuf[pos] = rec;
    }
  }
}

// one block per bucket (256 nodes): counting sort by local dst; emits csr_src, offs, dinv, pk
__global__ __launch_bounds__(256) void bucket_sort(const unsigned* __restrict__ gbuf,
                                                   const int* __restrict__ bhist,
                                                   const int* __restrict__ bbase,
                                                   const int* __restrict__ nt,
                                                   const int* __restrict__ nv,
                                                   int* __restrict__ csr_src,
                                                   int* __restrict__ offs,
                                                   float* __restrict__ dinv,
                                                   unsigned* __restrict__ pk) {
  __shared__ int lhist[256];
  __shared__ int lscan[256];
  __shared__ int lcur2[256];
  __shared__ int lcsr[EB_CAP];
  int tid = threadIdx.x;
  int b = blockIdx.x;
  int ebase = bbase[b];
  int bsize = bhist[b];
  lhist[tid] = 0;
  lcur2[tid] = 0;
  __syncthreads();
  for (int k = tid; k < bsize; k += 256)
    atomicAdd(&lhist[(gbuf[ebase + k] >> 17) & 255], 1);
  __syncthreads();
  lscan[tid] = lhist[tid];
  __syncthreads();
  for (int o = 1; o < 256; o <<= 1) {
    int a = (tid >= o) ? lscan[tid - o] : 0;
    __syncthreads();
    lscan[tid] += a;
    __syncthreads();
  }
  int i = (b << BSHIFT) + tid;
  if (i < NNODES) {
    int c = lhist[tid];
    offs[i] = ebase + (lscan[tid] - c);
    float dv = rsqrtf((float)c + 1.0f);
    dinv[i] = dv;
    pk[i] = (__float_as_uint(dv) & 0xFFFFFFF0u) |
            ((unsigned)nt[i] << 2) | (unsigned)nv[i];
  }
  for (int k = tid; k < bsize; k += 256) {
    unsigned e = gbuf[ebase + k];
    int l = (e >> 17) & 255;
    int p = atomicAdd(&lcur2[l], 1);
    int pos = (lscan[l] - lhist[l]) + p;
    if (pos < EB_CAP) lcsr[pos] = (int)(e & 0x1FFFFu);
  }
  __syncthreads();
  for (int k = tid; k < bsize; k += 256) csr_src[ebase + k] = lcsr[k];
}

// ---------------- layer 0: dictionary coefficients (pk: 1 gather/edge) ----------------

__device__ inline void pk_accum(unsigned p, float& c0, float& c1, float& c2, float& c3,
                                float& c4, float& c5, float& c6) {
  float dv = __uint_as_float(p & 0xFFFFFFF0u);
  int t = (p >> 2) & 3, v = p & 3;
  c0 += (t == 0) ? dv : 0.f;
  c1 += (t == 1) ? dv : 0.f;
  c2 += (t == 2) ? dv : 0.f;
  c3 += (t == 3) ? dv : 0.f;
  c4 += (v == 0) ? dv : 0.f;
  c5 += (v == 1) ? dv : 0.f;
  c6 += (v == 2) ? dv : 0.f;
}

__global__ __launch_bounds__(256) void coef_kernel(const int* __restrict__ offs,
                                                   const int* __restrict__ csr_src,
                                                   const unsigned* __restrict__ pk,
                                                   float* __restrict__ Cbuf) {
  int gid = blockIdx.x * 256 + threadIdx.x;
  int i = gid >> 2;
  int sl = gid & 3;
  if (i >= NNODES) return;
  int s0 = offs[i], s1 = offs[i + 1];
  float c0 = 0.f, c1 = 0.f, c2 = 0.f, c3 = 0.f, c4 = 0.f, c5 = 0.f, c6 = 0.f;
  int j = s0 + sl;
  for (; j + 28 < s1; j += 32) {
    int s_[8];
#pragma unroll
    for (int u = 0; u < 8; ++u) s_[u] = csr_src[j + 4 * u];
    unsigned p_[8];
#pragma unroll
    for (int u = 0; u < 8; ++u) p_[u] = pk[s_[u]];
#pragma unroll
    for (int u = 0; u < 8; ++u) pk_accum(p_[u], c0, c1, c2, c3, c4, c5, c6);
  }
  for (; j < s1; j += 4) pk_accum(pk[csr_src[j]], c0, c1, c2, c3, c4, c5, c6);
#pragma unroll
  for (int o = 1; o < 4; o <<= 1) {
    c0 += __shfl_xor(c0, o);
    c1 += __shfl_xor(c1, o);
    c2 += __shfl_xor(c2, o);
    c3 += __shfl_xor(c3, o);
    c4 += __shfl_xor(c4, o);
    c5 += __shfl_xor(c5, o);
    c6 += __shfl_xor(c6, o);
  }
  if (sl == 0) {
    unsigned pb = pk[i];
    float di = __uint_as_float(pb & 0xFFFFFFF0u);
    int t = (pb >> 2) & 3, v = pb & 3;
    c0 += (t == 0) ? di : 0.f;
    c1 += (t == 1) ? di : 0.f;
    c2 += (t == 2) ? di : 0.f;
    c3 += (t == 3) ? di : 0.f;
    c4 += (v == 0) ? di : 0.f;
    c5 += (v == 1) ? di : 0.f;
    c6 += (v == 2) ? di : 0.f;
    float4 lo = {c0, c1, c2, c3};
    float4 hi = {c4, c5, c6, 0.f};
    *(float4*)(Cbuf + (size_t)i * 8) = lo;
    *(float4*)(Cbuf + (size_t)i * 8 + 4) = hi;
  }
}

// ---------------- fused layer-1 GEMM: xws = dinv * (relu(dinv*(C@TW)+b0) @ W1) ----------------

__global__ __launch_bounds__(256) void gemm1_kernel(const float* __restrict__ Cbuf,
                                                    const float* __restrict__ TW,
                                                    const float* __restrict__ b0,
                                                    const ushort* __restrict__ wb,
                                                    const float* __restrict__ dinv,
                                                    ushort* __restrict__ out) {
  __shared__ ushort Ws[32 * 64 * 8];  // 32 KiB, B-fragment order
  __shared__ float TWs[7 * 128];
  __shared__ float b0s[128];
  int tid = threadIdx.x;
  for (int g = tid; g < 2048; g += 256) {
    int kt = g >> 6, l = g & 63;
    int ks = kt >> 3, t = kt & 7;
    int kb = ks * 32 + ((l >> 4) << 3);
    int col = t * 16 + (l & 15);
#pragma unroll
    for (int j = 0; j < 8; ++j) Ws[g * 8 + j] = wb[(kb + j) * DIM + col];
  }
  for (int g = tid; g < 896; g += 256) TWs[g] = TW[g];
  if (tid < 128) b0s[tid] = b0[tid];
  __syncthreads();
  int w = tid >> 6, lane = tid & 63;
  for (int tile = blockIdx.x * 4 + w; tile < NNODES / 16; tile += gridDim.x * 4) {
    int row0 = tile * 16;
    int arow = row0 + (lane & 15);
    float di = dinv[arow];
    float4 Clo = *(const float4*)(Cbuf + (size_t)arow * 8);
    float4 Chi = *(const float4*)(Cbuf + (size_t)arow * 8 + 4);
    float C[7] = {Clo.x, Clo.y, Clo.z, Clo.w, Chi.x, Chi.y, Chi.z};
    f32x4 acc[8];
#pragma unroll
    for (int t = 0; t < 8; ++t) acc[t] = {0.f, 0.f, 0.f, 0.f};
#pragma unroll
    for (int ks = 0; ks < 4; ++ks) {
      int d0 = ((lane >> 4) << 3) + ks * 32;
      bf16x8 a;
#pragma unroll
      for (int d = 0; d < 8; ++d) {
        float dot = 0.f;
#pragma unroll
        for (int k = 0; k < 7; ++k) dot += C[k] * TWs[k * 128 + d0 + d];
        float s = fmaxf(di * dot + b0s[d0 + d], 0.f);
        a[d] = (short)f2bf(s);
      }
#pragma unroll
      for (int t = 0; t < 8; ++t) {
        bf16x8 bfr = *(const bf16x8*)&Ws[((ks * 8 + t) * 64 + lane) * 8];
        acc[t] = __builtin_amdgcn_mfma_f32_16x16x32_bf16(a, bfr, acc[t], 0, 0, 0);
      }
    }
    int rbase = row0 + ((lane >> 4) << 2);
    int cbase = lane & 15;
    float4 dv = *(const float4*)(dinv + rbase);
    float dvr[4] = {dv.x, dv.y, dv.z, dv.w};
#pragma unroll
    for (int t = 0; t < 8; ++t)
#pragma unroll
      for (int r = 0; r < 4; ++r)
        out[(size_t)(rbase + r) * DIM + t * 16 + cbase] = f2bf(acc[t][r] * dvr[r]);
  }
}

// ---------------- MFMA GEMM (layer 2): xws = dinv * (h @ W) ----------------

__global__ __launch_bounds__(256) void gemm_kernel(const ushort* __restrict__ h,
                                                   const ushort* __restrict__ wb,
                                                   const float* __restrict__ dinv,
                                                   ushort* __restrict__ out) {
  __shared__ ushort Ws[32 * 64 * 8];
  int tid = threadIdx.x;
  for (int g = tid; g < 2048; g += 256) {
    int kt = g >> 6, l = g & 63;
    int ks = kt >> 3, t = kt & 7;
    int kb = ks * 32 + ((l >> 4) << 3);
    int col = t * 16 + (l & 15);
#pragma unroll
    for (int j = 0; j < 8; ++j) Ws[g * 8 + j] = wb[(kb + j) * DIM + col];
  }
  __syncthreads();
  int w = tid >> 6, lane = tid & 63;
  for (int tile = blockIdx.x * 4 + w; tile < NNODES / 16; tile += gridDim.x * 4) {
    int row0 = tile * 16;
    const ushort* hrow = h + (size_t)(row0 + (lane & 15)) * DIM + ((lane >> 4) << 3);
    f32x4 acc[8];
#pragma unroll
    for (int t = 0; t < 8; ++t) acc[t] = {0.f, 0.f, 0.f, 0.f};
#pragma unroll
    for (int ks = 0; ks < 4; ++ks) {
      bf16x8 a = *(const bf16x8*)(hrow + ks * 32);
#pragma unroll
      for (int t = 0; t < 8; ++t) {
        bf16x8 b = *(const bf16x8*)&Ws[((ks * 8 + t) * 64 + lane) * 8];
        acc[t] = __builtin_amdgcn_mfma_f32_16x16x32_bf16(a, b, acc[t], 0, 0, 0);
      }
    }
    int rbase = row0 + ((lane >> 4) << 2);
    int cbase = lane & 15;
    float4 dv = *(const float4*)(dinv + rbase);
    float dvr[4] = {dv.x, dv.y, dv.z, dv.w};
#pragma unroll
    for (int t = 0; t < 8; ++t)
#pragma unroll
      for (int r = 0; r < 4; ++r)
        out[(size_t)(rbase + r) * DIM + t * 16 + cbase] = f2bf(acc[t][r] * dvr[r]);
  }
}

// ---------------- aggregation: one wave per node, 16-deep gather (round-12 best: 66.0 us) ----------------

__global__ __launch_bounds__(256, 8) void agg_kernel(const ushort* __restrict__ xws,
                                                     const int* __restrict__ offs,
                                                     const int* __restrict__ csr_src,
                                                     const float* __restrict__ dinv,
                                                     const float* __restrict__ bias,
                                                     ushort* __restrict__ outb, int relu) {
  int i = blockIdx.x * 4 + (threadIdx.x >> 6);
  if (i >= NNODES) return;
  int lane = threadIdx.x & 63;
  int s0 = offs[i], s1 = offs[i + 1];
  float ax = 0.f, ay = 0.f;
  int j = s0;
  for (; j + 16 <= s1; j += 16) {
    int s[16];
#pragma unroll
    for (int u = 0; u < 16; ++u) s[u] = csr_src[j + u];
    unsigned p[16];
#pragma unroll
    for (int u = 0; u < 16; ++u)
      p[u] = *(const unsigned*)(xws + (size_t)s[u] * DIM + lane * 2);
#pragma unroll
    for (int u = 0; u < 16; ++u) {
      ax += bf2f((ushort)(p[u] & 0xffffu));
      ay += bf2f((ushort)(p[u] >> 16));
    }
  }
  for (; j + 4 <= s1; j += 4) {
    int s[4];
#pragma unroll
    for (int u = 0; u < 4; ++u) s[u] = csr_src[j + u];
    unsigned p[4];
#pragma unroll
    for (int u = 0; u < 4; ++u)
      p[u] = *(const unsigned*)(xws + (size_t)s[u] * DIM + lane * 2);
#pragma unroll
    for (int u = 0; u < 4; ++u) {
      ax += bf2f((ushort)(p[u] & 0xffffu));
      ay += bf2f((ushort)(p[u] >> 16));
    }
  }
  for (; j < s1; ++j) {
    int sa = csr_src[j];
    unsigned pa = *(const unsigned*)(xws + (size_t)sa * DIM + lane * 2);
    ax += bf2f((ushort)(pa & 0xffffu));
    ay += bf2f((ushort)(pa >> 16));
  }
  unsigned ps = *(const unsigned*)(xws + (size_t)i * DIM + lane * 2);
  ax += bf2f((ushort)(ps & 0xffffu));
  ay += bf2f((ushort)(ps >> 16));
  float di = dinv[i];
  float2 b = *(const float2*)(bias + lane * 2);
  float vx = di * ax + b.x;
  float vy = di * ay + b.y;
  if (relu) { vx = fmaxf(vx, 0.f); vy = fmaxf(vy, 0.f); }
  *(unsigned*)(outb + (size_t)i * DIM + lane * 2) =
      ((unsigned)f2bf(vy) << 16) | f2bf(vx);
}

// ---------------- readout (bf16 h) ----------------

__global__ __launch_bounds__(128) void readout_kernel(const ushort* __restrict__ h,
                                                      const int* __restrict__ batch,
                                                      unsigned* __restrict__ gmaxk,
                                                      float* __restrict__ gsum) {
  int d = threadIdx.x;
  int start = blockIdx.x * 128;
  if (start >= NNODES) return;
  int end = min(start + 128, NNODES);
  int cur = batch[start];
  float s = 0.f, m = -INFINITY;
  for (int i = start; i < end; ++i) {
    int g = batch[i];
    float v = bf2f(h[(size_t)i * DIM + d]);
    if (g != cur) {
      atomicAdd(&gsum[cur * DIM + d], s);
      atomicMax(&gmaxk[cur * DIM + d], fkey(m));
      cur = g; s = 0.f; m = -INFINITY;
    }
    s += v;
    m = fmaxf(m, v);
  }
  atomicAdd(&gsum[cur * DIM + d], s);
  atomicMax(&gmaxk[cur * DIM + d], fkey(m));
}

__global__ void pack_kernel(const unsigned* __restrict__ gmaxk,
                            const float* __restrict__ gsum, float* __restrict__ out) {
  int idx = blockIdx.x * blockDim.x + threadIdx.x;
  if (idx >= NGRAPHS * 256) return;
  int g = idx >> 8, d = idx & 255;
  float v = (d < 128) ? fdecode(gmaxk[g * DIM + d]) : gsum[g * DIM + (d - 128)];
  out[idx] = rintf(v * 1000.0f) / 1000.0f;
}

// ---------------- launch ----------------

extern "C" void kernel_launch(void* const* d_in, const int* in_sizes, int n_in,
                              void* d_out, int out_size, void* d_ws, size_t ws_size,
                              hipStream_t stream) {
  const int* node_type = (const int*)d_in[0];
  const int* ninv      = (const int*)d_in[1];
  const int* edge      = (const int*)d_in[2];
  const int* batch     = (const int*)d_in[3];
  const float* emb_type = (const float*)d_in[4];
  const float* emb_inv  = (const float*)d_in[5];
  const float* W0 = (const float*)d_in[6];
  const float* B[3] = {(const float*)d_in[7], (const float*)d_in[9], (const float*)d_in[11]};
  const float* W1 = (const float*)d_in[8];
  const float* W2 = (const float*)d_in[10];
  const int* srcp = edge;
  const int* dstp = edge + NEDGES;
  float* out = (float*)d_out;

  char* ws = (char*)d_ws;
  auto alloc = [&](size_t bytes) {
    char* p = ws;
    ws += (bytes + 255) & ~(size_t)255;
    return p;
  };
  ushort* hA     = (ushort*)alloc((size_t)NNODES * DIM * 2);
  ushort* xws    = (ushort*)alloc((size_t)NNODES * DIM * 2);
  float* dinv    = (float*)alloc((size_t)NNODES * 4);
  unsigned* pk   = (unsigned*)alloc((size_t)NNODES * 4);
  int* offs      = (int*)alloc((size_t)(NNODES + 1) * 4);
  int* csr_src   = (int*)alloc((size_t)NEDGES * 4);
  unsigned* gbuf = (unsigned*)alloc((size_t)NEDGES * 4);
  float* Cbuf    = (float*)alloc((size_t)NNODES * 8 * 4);
  unsigned* gmaxk = (unsigned*)alloc((size_t)NGRAPHS * DIM * 4);   // contiguous with
  float* gsum    = (float*)alloc((size_t)NGRAPHS * DIM * 4);       // gsum and bhist
  int* bhist     = (int*)alloc((size_t)NB * 4);
  int* bbase     = (int*)alloc((size_t)(NB + 1) * 4);
  int* blockhist = (int*)alloc((size_t)SC_BLOCKS * NB * 4);
  int* blockbase = (int*)alloc((size_t)SC_BLOCKS * NB * 4);
  float* TW      = (float*)alloc((size_t)7 * DIM * 4);
  ushort* wbf    = (ushort*)alloc((size_t)2 * DIM * DIM * 2);

  // gmaxk | gsum | bhist are contiguous
  hipMemsetAsync(gmaxk, 0, (size_t)NGRAPHS * DIM * 4 * 2 + NB * 4, stream);

  histprep_kernel<<<SC_BLOCKS + 39, 256, 0, stream>>>(dstp, blockhist, bhist,
                                                      emb_type, emb_inv, W0, W1, W2,
                                                      TW, wbf);
  scanB_kernel<<<NB, 512, 0, stream>>>(bhist, blockhist, bbase, blockbase, offs);
  scatter2_kernel<<<SC_BLOCKS, 256, 0, stream>>>(srcp, dstp, blockbase, gbuf);
  bucket_sort<<<NB, 256, 0, stream>>>(gbuf, bhist, bbase, node_type, ninv,
                                      csr_src, offs, dinv, pk);

  coef_kernel<<<(NNODES * 4 + 255) / 256, 256, 0, stream>>>(offs, csr_src, pk, Cbuf);

  // layer 1: fused h1-synthesis GEMM, then aggregate
  gemm1_kernel<<<1024, 256, 0, stream>>>(Cbuf, TW, B[0], wbf, dinv, xws);
  agg_kernel<<<NNODES / 4, 256, 0, stream>>>(xws, offs, csr_src, dinv, B[1], hA, 1);

  // layer 2
  gemm_kernel<<<1024, 256, 0, stream>>>(hA, wbf + (size_t)DIM * DIM, dinv, xws);
  agg_kernel<<<NNODES / 4, 256, 0, stream>>>(xws, offs, csr_src, dinv, B[2], hA, 0);

  readout_kernel<<<(NNODES + 127) / 128, 128, 0, stream>>>(hA, batch, gmaxk, gsum);
  pack_kernel<<<64, 256, 0, stream>>>(gmaxk, gsum, out);
}